// Round 11
// baseline (143.375 us; speedup 1.0000x reference)
//
#include <hip/hip_runtime.h>
#include <stdint.h>

#define N_CODES 65536
#define CB_DIM 8
#define B_ROWS 16
#define X_COLS 2048
#define M_ROWS 4096            // 16*2048/8
#define RPB 8                  // rows per argmin block
#define AT 1024                // argmin threads/block: 16 waves, 2 blk/CU -> 32 waves/CU
#define NWAVE (AT / 64)

// workspace byte offsets (total 2,375,936 B <= proven 2,507,008 capacity).
// nu (=-2*x/scale, 128 KB) lives in d_out until gather overwrites it.
#define WS_SCALE 0             // 16 f32                        (ends 256, padded)
#define WS_IDX   256           // 4096 i32                      (ends 16640)
#define WS_SUMS  16640         // 65536*8 f32                   (ends 2113792)
#define WS_CNT   2113792       // 65536 f32                     (ends 2375936)

// distance + min-track for one code against 8 rows. nu[] comes from a
// UNIFORM global address -> s_load -> SGPRs (proven R5/6/9/10: SGPR 96,
// VGPR 36, absmax 0.0). One SGPR source per v_fma (legal). fma chain order
// unchanged since round 0 -> bit-identical distances.
#define CODE_BODY(C0, C1, NIDX)                                            \
    {                                                                      \
        float hn = (C0).x * (C0).x;                                        \
        hn = fmaf((C0).y, (C0).y, hn);                                     \
        hn = fmaf((C0).z, (C0).z, hn);                                     \
        hn = fmaf((C0).w, (C0).w, hn);                                     \
        hn = fmaf((C1).x, (C1).x, hn);                                     \
        hn = fmaf((C1).y, (C1).y, hn);                                     \
        hn = fmaf((C1).z, (C1).z, hn);                                     \
        hn = fmaf((C1).w, (C1).w, hn);                                     \
        _Pragma("unroll")                                                  \
        for (int r = 0; r < RPB; r++) {                                    \
            float d = hn;                                                  \
            d = fmaf(nu[r * 8 + 0], (C0).x, d);                            \
            d = fmaf(nu[r * 8 + 1], (C0).y, d);                            \
            d = fmaf(nu[r * 8 + 2], (C0).z, d);                            \
            d = fmaf(nu[r * 8 + 3], (C0).w, d);                            \
            d = fmaf(nu[r * 8 + 4], (C1).x, d);                            \
            d = fmaf(nu[r * 8 + 5], (C1).y, d);                            \
            d = fmaf(nu[r * 8 + 6], (C1).z, d);                            \
            d = fmaf(nu[r * 8 + 7], (C1).w, d);                            \
            if (d < best[r]) { best[r] = d; bidx[r] = (NIDX); }            \
        }                                                                  \
    }

// ------- prep: per-row scale + nu = -2*(x/scale) into OUT -------
// Reduction order VERBATIM the passing kernels' -> bit-identical scale.
__global__ __launch_bounds__(256) void prep_kernel(const float* __restrict__ x,
                                                   float* __restrict__ scale_out,
                                                   float* __restrict__ nuout) {
    int tid = threadIdx.x;
    int xr = blockIdx.x;                               // 0..15
    const float4* xv = (const float4*)(x + xr * X_COLS);
    float4 q0 = xv[tid];
    float4 q1 = xv[tid + 256];
    float s = fabsf(q0.x) + fabsf(q0.y) + fabsf(q0.z) + fabsf(q0.w)
            + fabsf(q1.x) + fabsf(q1.y) + fabsf(q1.z) + fabsf(q1.w);
    #pragma unroll
    for (int off = 32; off > 0; off >>= 1) s += __shfl_down(s, off, 64);
    __shared__ float ls[4];
    __shared__ float scale_sh;
    int wave = tid >> 6, lane = tid & 63;
    if (lane == 0) ls[wave] = s;
    __syncthreads();
    if (tid == 0) {
        float t = (ls[0] + ls[1] + ls[2] + ls[3]) * (1.0f / (float)X_COLS);
        scale_sh = t;
        scale_out[xr] = t;
    }
    __syncthreads();
    float scale = scale_sh;

    // nu = -2*(x/scale): same op composition as the passing kernels.
    float4 n0, n1;
    n0.x = -2.0f * (q0.x / scale);  n0.y = -2.0f * (q0.y / scale);
    n0.z = -2.0f * (q0.z / scale);  n0.w = -2.0f * (q0.w / scale);
    n1.x = -2.0f * (q1.x / scale);  n1.y = -2.0f * (q1.y / scale);
    n1.z = -2.0f * (q1.z / scale);  n1.w = -2.0f * (q1.w / scale);
    float4* np = (float4*)(nuout + xr * X_COLS);
    np[tid]       = n0;
    np[tid + 256] = n1;
}

// ---------------- argmin over the FULL codebook, 1024-thread blocks ----------------
// ROUND-11: R7's block shape + R9's allocator fix + R10's register reduce.
// Cross-round occupancy data: 512-thr blocks NEVER exceed ~16 waves/CU
// (R6 37%, R9 50%, R10 49% even at 512B LDS -> LDS-granule theory falsified);
// the only config >16 waves/CU was R7's 1024-thr block (68%). So: 16
// waves/block, 2 blocks/CU = 32 waves/CU nominal. launch_bounds(1024,4)
// leaves the allocator at its natural ~36-40 VGPR (R7's (1024,8) forced 32
// -> scratch spill, WRITE_SIZE 6.4MB). LDS = 1KB (register shuffle reduce).
// No code split: 512 blocks, full codebook each; L2 traffic unchanged (1GB).
__global__ __launch_bounds__(AT, 4) void argmin_kernel(const float* __restrict__ cb,
                                                       const float* __restrict__ nuarr,
                                                       int* __restrict__ indices,
                                                       float* __restrict__ sums,
                                                       float* __restrict__ counts) {
    int tid = threadIdx.x;
    int m0 = blockIdx.x * RPB;

    // 64 wave-uniform nu via uniform-address loads -> s_load -> SGPRs.
    const float* __restrict__ up = nuarr + (size_t)m0 * CB_DIM;
    float nu[RPB * CB_DIM];
    #pragma unroll
    for (int i = 0; i < RPB * CB_DIM; i++) nu[i] = up[i];

    float best[RPB];
    int   bidx[RPB];
    #pragma unroll
    for (int r = 0; r < RPB; r++) { best[r] = 3.4e38f; bidx[r] = 0; }

    // ---- 4-wide ping-pong over all 65536 codes.
    // Coverage: tid + AT*k, k=0..63 (ascending per thread -> lowest-index
    // tie-break preserved under ANY partition via the u64-key min reduce).
    // 16 groups of 4; 15 iterations + peel.
    // Max prefetch: j=14 -> n+7*AT = tid + 57344 + 7168 <= 65535.
    const float4* cp = (const float4*)cb;
    int n = tid;
    float4 a0 = cp[2 * n],            a1 = cp[2 * n + 1];
    float4 b0 = cp[2 * (n + AT)],     b1 = cp[2 * (n + AT) + 1];
    float4 c0 = cp[2 * (n + 2 * AT)], c1 = cp[2 * (n + 2 * AT) + 1];
    float4 d0 = cp[2 * (n + 3 * AT)], d1 = cp[2 * (n + 3 * AT) + 1];

    for (int j = 0; j < 15; j++) {
        CODE_BODY(a0, a1, n)
        CODE_BODY(b0, b1, n + AT)
        a0 = cp[2 * (n + 4 * AT)]; a1 = cp[2 * (n + 4 * AT) + 1];
        b0 = cp[2 * (n + 5 * AT)]; b1 = cp[2 * (n + 5 * AT) + 1];
        CODE_BODY(c0, c1, n + 2 * AT)
        CODE_BODY(d0, d1, n + 3 * AT)
        c0 = cp[2 * (n + 6 * AT)]; c1 = cp[2 * (n + 6 * AT) + 1];
        d0 = cp[2 * (n + 7 * AT)]; d1 = cp[2 * (n + 7 * AT) + 1];
        n += 4 * AT;
    }
    CODE_BODY(a0, a1, n)
    CODE_BODY(b0, b1, n + AT)
    CODE_BODY(c0, c1, n + 2 * AT)
    CODE_BODY(d0, d1, n + 3 * AT)

    // ---- in-register wave64 u64-min reduce (6 shfl rounds, proven R10) ----
    unsigned long long key[RPB];
    #pragma unroll
    for (int r = 0; r < RPB; r++) {
        unsigned int b = __float_as_uint(best[r]);
        unsigned int kk = b ^ ((unsigned int)((int)b >> 31) | 0x80000000u);
        key[r] = ((unsigned long long)kk << 32) | (unsigned int)bidx[r];
    }
    #pragma unroll
    for (int off = 32; off > 0; off >>= 1) {
        #pragma unroll
        for (int r = 0; r < RPB; r++) {
            unsigned long long o = __shfl_down(key[r], off, 64);
            if (o < key[r]) key[r] = o;
        }
    }

    // ---- cross-wave finish: 16 waves x 8 rows x u64 = 1 KB LDS ----
    __shared__ unsigned long long wred[NWAVE][RPB];
    int wave = tid >> 6, lane = tid & 63;
    if (lane == 0) {
        #pragma unroll
        for (int r = 0; r < RPB; r++) wred[wave][r] = key[r];
    }
    __syncthreads();

    // thread r < 8 finalizes row r: write index + zero the winner's
    // sums/counts (winner unique per row again — no halves; kernel boundary
    // orders the zeros before accum's atomics).
    if (tid < RPB) {
        unsigned long long m = wred[0][tid];
        #pragma unroll
        for (int w = 1; w < NWAVE; w++) {
            unsigned long long o = wred[w][tid];
            if (o < m) m = o;
        }
        int idx = (int)(m & 0xFFFFFFFFull);
        indices[m0 + tid] = idx;
        counts[idx] = 0.f;
        float4 z = make_float4(0.f, 0.f, 0.f, 0.f);
        float4* sp = (float4*)(sums + (size_t)idx * CB_DIM);
        sp[0] = z;
        sp[1] = z;
    }
}

// ---------------- segment-sum via atomics (128 blocks, 1 thr/(m,k)) ----------------
// nuarr(=out) holds -2u; sums accumulate -2*sum(u) EXACTLY (power-of-two
// scaling commutes with fp rounding, any atomic order). gather compensates.
__global__ __launch_bounds__(256) void accum_kernel(const int* __restrict__ indices,
                                                    const float* __restrict__ nuarr,
                                                    float* __restrict__ sums,
                                                    float* __restrict__ counts) {
    int e = blockIdx.x * blockDim.x + threadIdx.x;     // 0..32767, one per (m,k)
    int m = e >> 3, k = e & 7;
    int idx = indices[m];
    if (k == 0) atomicAdd(&counts[idx], 1.0f);
    atomicAdd(&sums[(size_t)idx * CB_DIM + k], nuarr[e]);
}

// ---------------- gather + rescale (overwrites out; nu no longer needed) ----------------
__global__ __launch_bounds__(256) void gather_kernel(const int* __restrict__ indices,
                                                     const float* __restrict__ sums,
                                                     const float* __restrict__ counts,
                                                     const float* __restrict__ scale,
                                                     float* __restrict__ out) {
    int e = blockIdx.x * blockDim.x + threadIdx.x;     // 0..32767
    int m = e >> 3, k = e & 7;
    int idx = indices[m];
    float c = counts[idx];
    c = c < 1.f ? 1.f : c;
    // sums = -2*S exactly; (-0.5f)*(sums/c) == S/c bit-exactly.
    out[e] = scale[e >> 11] * (-0.5f * (sums[(size_t)idx * CB_DIM + k] / c));
}

extern "C" void kernel_launch(void* const* d_in, const int* in_sizes, int n_in,
                              void* d_out, int out_size, void* d_ws, size_t ws_size,
                              hipStream_t stream) {
    const float* x  = (const float*)d_in[0];           // [16,2048]
    const float* cb = (const float*)d_in[1];           // [65536,8]
    char* ws = (char*)d_ws;
    float* scale   = (float*)(ws + WS_SCALE);
    int*   indices = (int*)(ws + WS_IDX);
    float* sums    = (float*)(ws + WS_SUMS);
    float* counts  = (float*)(ws + WS_CNT);
    float* out     = (float*)d_out;
    // nu = -2*(x/scale) is staged in d_out (32768 f32 = exactly out's size):
    // prep writes it, argmin s_loads it, accum reads it, gather overwrites it.
    // Every consumer is separated by a kernel boundary; out is fully
    // rewritten each replay -> graph-replay deterministic.
    float* nuarr = out;

    prep_kernel  <<<B_ROWS, 256, 0, stream>>>(x, scale, nuarr);
    argmin_kernel<<<M_ROWS / RPB, AT, 0, stream>>>(cb, nuarr, indices, sums, counts);
    accum_kernel <<<(M_ROWS * CB_DIM) / 256, 256, 0, stream>>>(indices, nuarr, sums, counts);
    gather_kernel<<<(B_ROWS * X_COLS) / 256, 256, 0, stream>>>(indices, sums, counts, scale, out);
}

// Round 12
// 137.730 us; speedup vs baseline: 1.0410x; 1.0410x over previous
//
#include <hip/hip_runtime.h>
#include <stdint.h>

#define N_CODES 65536
#define CB_DIM 8
#define B_ROWS 16
#define X_COLS 2048
#define M_ROWS 4096            // 16*2048/8
#define RPB 8                  // rows per argmin block
#define AT 512                 // argmin threads/block (R10 config: best argmin = 89.3us)
#define NWAVE (AT / 64)

// workspace byte offsets (total 2,425,088 B <= proven 2,507,008 capacity)
#define WS_SCALE 0             // 16 f32                       (ends 256, padded)
#define WS_PART  256           // 4096*2 u64 partial keys      (ends 65792)
#define WS_SUMS  65792         // 65536*8 f32                  (ends 2162944)
#define WS_CNT   2162944       // 65536 f32                    (ends 2425088)

// ROUND-12 REFORMULATION: argmin_n [ ||c||^2 - 2 sum u_j c_j ]  (u = x/s)
//   == argmax_n [ sum x_j c_j  - 0.5*s*||c||^2 ]   (scaled by -s/2 < 0... s>0)
// This lets the per-row operand be RAW x -> s_load directly from the input
// (uniform address -> SGPRs, the R5/9/10-proven path) with all-POSITIVE fma
// sources, killing the prep kernel (and one ~10us dispatch boundary).
// sx[] in SGPRs; one SGPR source per v_fma (legal). Max-tracking with strict
// '>' + ascending visit order keeps lowest-index-on-tie semantics.
#define CODE_BODY(C0, C1, NIDX)                                            \
    {                                                                      \
        float hn = (C0).x * (C0).x;                                        \
        hn = fmaf((C0).y, (C0).y, hn);                                     \
        hn = fmaf((C0).z, (C0).z, hn);                                     \
        hn = fmaf((C0).w, (C0).w, hn);                                     \
        hn = fmaf((C1).x, (C1).x, hn);                                     \
        hn = fmaf((C1).y, (C1).y, hn);                                     \
        hn = fmaf((C1).z, (C1).z, hn);                                     \
        hn = fmaf((C1).w, (C1).w, hn);                                     \
        float hs = hw * hn;                                                \
        _Pragma("unroll")                                                  \
        for (int r = 0; r < RPB; r++) {                                    \
            float d = hs;                                                  \
            d = fmaf(sx[r * 8 + 0], (C0).x, d);                            \
            d = fmaf(sx[r * 8 + 1], (C0).y, d);                            \
            d = fmaf(sx[r * 8 + 2], (C0).z, d);                            \
            d = fmaf(sx[r * 8 + 3], (C0).w, d);                            \
            d = fmaf(sx[r * 8 + 4], (C1).x, d);                            \
            d = fmaf(sx[r * 8 + 5], (C1).y, d);                            \
            d = fmaf(sx[r * 8 + 6], (C1).z, d);                            \
            d = fmaf(sx[r * 8 + 7], (C1).w, d);                            \
            if (d > best[r]) { best[r] = d; bidx[r] = (NIDX); }            \
        }                                                                  \
    }

// ---------------- fused: scale + argmax over half the codebook ----------------
// R10 config frozen: grid 1024 (512 rg x 2 halves), 512 thr, LB(512,4).
// Occupancy lesson (R6..R11): dur is flat at 89-97us across 37-50% occ;
// stop chasing the scheduler. This round attacks the DISPATCH TAIL instead.
__global__ __launch_bounds__(AT, 4) void argmin_kernel(const float* __restrict__ x,
                                                       const float* __restrict__ cb,
                                                       float* __restrict__ scale_out,
                                                       unsigned long long* __restrict__ part,
                                                       float* __restrict__ sums,
                                                       float* __restrict__ counts) {
    int tid = threadIdx.x;
    int rg  = blockIdx.x >> 1;                         // row-group 0..511
    int h   = blockIdx.x & 1;                          // code-space half
    int m0  = rg * RPB;
    int xr  = m0 >> 8;                                 // this block's x row

    // ---- scale = mean(|x[xr,:]|), VERBATIM prior reduction tree (tid<256
    // does 8 elems; 4-wave combine) -> bit-identical scale to all passing
    // rounds. Threads 256-511 idle ~20 instrs (negligible, once per kernel).
    __shared__ float ls[4];
    __shared__ float scale_sh;
    if (tid < 256) {
        const float4* xv = (const float4*)(x + xr * X_COLS);
        float4 q0 = xv[tid];
        float4 q1 = xv[tid + 256];
        float s = fabsf(q0.x) + fabsf(q0.y) + fabsf(q0.z) + fabsf(q0.w)
                + fabsf(q1.x) + fabsf(q1.y) + fabsf(q1.z) + fabsf(q1.w);
        #pragma unroll
        for (int off = 32; off > 0; off >>= 1) s += __shfl_down(s, off, 64);
        int wave = tid >> 6, lane = tid & 63;
        if (lane == 0) ls[wave] = s;
    }
    __syncthreads();
    if (tid == 0) {
        float t = (ls[0] + ls[1] + ls[2] + ls[3]) * (1.0f / (float)X_COLS);
        scale_sh = t;
        if ((blockIdx.x & 63) == 0) scale_out[xr] = t;  // 64 blocks per x-row
    }
    __syncthreads();
    float hw = -0.5f * scale_sh;                       // per-code ||c||^2 weight

    // ---- 64 wave-uniform RAW x values via uniform-address loads -> s_load
    // -> SGPRs (the proven scalar path; no prep kernel needed).
    const float* __restrict__ up = x + (size_t)m0 * CB_DIM;
    float sx[RPB * CB_DIM];
    #pragma unroll
    for (int i = 0; i < RPB * CB_DIM; i++) sx[i] = up[i];

    float best[RPB];
    int   bidx[RPB];
    #pragma unroll
    for (int r = 0; r < RPB; r++) { best[r] = -3.4e38f; bidx[r] = 0; }

    // ---- 4-wide ping-pong over this half's 32768 codes (R10 loop verbatim).
    // Coverage: (h<<15)+tid+AT*k, k=0..63. Max prefetch j=14 -> <= 65535.
    const float4* cp = (const float4*)cb;
    int n = (h << 15) + tid;
    float4 a0 = cp[2 * n],            a1 = cp[2 * n + 1];
    float4 b0 = cp[2 * (n + AT)],     b1 = cp[2 * (n + AT) + 1];
    float4 c0 = cp[2 * (n + 2 * AT)], c1 = cp[2 * (n + 2 * AT) + 1];
    float4 d0 = cp[2 * (n + 3 * AT)], d1 = cp[2 * (n + 3 * AT) + 1];

    for (int j = 0; j < 15; j++) {
        CODE_BODY(a0, a1, n)
        CODE_BODY(b0, b1, n + AT)
        a0 = cp[2 * (n + 4 * AT)]; a1 = cp[2 * (n + 4 * AT) + 1];
        b0 = cp[2 * (n + 5 * AT)]; b1 = cp[2 * (n + 5 * AT) + 1];
        CODE_BODY(c0, c1, n + 2 * AT)
        CODE_BODY(d0, d1, n + 3 * AT)
        c0 = cp[2 * (n + 6 * AT)]; c1 = cp[2 * (n + 6 * AT) + 1];
        d0 = cp[2 * (n + 7 * AT)]; d1 = cp[2 * (n + 7 * AT) + 1];
        n += 4 * AT;
    }
    CODE_BODY(a0, a1, n)
    CODE_BODY(b0, b1, n + AT)
    CODE_BODY(c0, c1, n + 2 * AT)
    CODE_BODY(d0, d1, n + 3 * AT)

    // ---- in-register wave64 reduce (R10-proven). For MAX with lowest-index
    // tie-break: key = (~sortable(d) << 32) | idx; u64-MIN picks largest d,
    // then smallest idx.
    unsigned long long key[RPB];
    #pragma unroll
    for (int r = 0; r < RPB; r++) {
        unsigned int b = __float_as_uint(best[r]);
        unsigned int kk = b ^ ((unsigned int)((int)b >> 31) | 0x80000000u);
        kk = ~kk;
        key[r] = ((unsigned long long)kk << 32) | (unsigned int)bidx[r];
    }
    #pragma unroll
    for (int off = 32; off > 0; off >>= 1) {
        #pragma unroll
        for (int r = 0; r < RPB; r++) {
            unsigned long long o = __shfl_down(key[r], off, 64);
            if (o < key[r]) key[r] = o;
        }
    }

    // ---- cross-wave finish: 8 waves x 8 rows x u64 = 512 B LDS ----
    __shared__ unsigned long long wred[NWAVE][RPB];
    int wave = tid >> 6, lane = tid & 63;
    if (lane == 0) {
        #pragma unroll
        for (int r = 0; r < RPB; r++) wred[wave][r] = key[r];
    }
    __syncthreads();

    // thread r < 8: partial winner for this half + zero that candidate's
    // sums/counts (final winner is one of the two halves' winners -> zeroed;
    // zeroing a loser is benign; kernel boundary orders zeros before accum).
    if (tid < RPB) {
        unsigned long long m = wred[0][tid];
        #pragma unroll
        for (int w = 1; w < NWAVE; w++) {
            unsigned long long o = wred[w][tid];
            if (o < m) m = o;
        }
        part[(size_t)(m0 + tid) * 2 + h] = m;
        int idx = (int)(m & 0xFFFFFFFFull);
        counts[idx] = 0.f;
        float4 z = make_float4(0.f, 0.f, 0.f, 0.f);
        float4* sp = (float4*)(sums + (size_t)idx * CB_DIM);
        sp[0] = z;
        sp[1] = z;
    }
}

// ---------------- merge halves + segment-sum of u = x/scale via atomics ----------------
// u computed on the fly (same division op as the reference); singleton-
// dominated clusters (4096 rows / 65536 codes) keep sums near-exact.
__global__ __launch_bounds__(256) void accum_kernel(const unsigned long long* __restrict__ part,
                                                    const float* __restrict__ x,
                                                    const float* __restrict__ scale,
                                                    float* __restrict__ sums,
                                                    float* __restrict__ counts) {
    int e = blockIdx.x * blockDim.x + threadIdx.x;     // 0..32767, one per (m,k)
    int m = e >> 3, k = e & 7;
    unsigned long long k0 = part[2 * m], k1 = part[2 * m + 1];
    unsigned long long kk = k1 < k0 ? k1 : k0;
    int idx = (int)(kk & 0xFFFFFFFFull);
    if (k == 0) atomicAdd(&counts[idx], 1.0f);
    float u = x[e] / scale[e >> 11];                   // e>>11 = x row (2048/row)
    atomicAdd(&sums[(size_t)idx * CB_DIM + k], u);
}

// ---------------- gather + rescale ----------------
__global__ __launch_bounds__(256) void gather_kernel(const unsigned long long* __restrict__ part,
                                                     const float* __restrict__ sums,
                                                     const float* __restrict__ counts,
                                                     const float* __restrict__ scale,
                                                     float* __restrict__ out) {
    int e = blockIdx.x * blockDim.x + threadIdx.x;     // 0..32767
    int m = e >> 3, k = e & 7;
    unsigned long long k0 = part[2 * m], k1 = part[2 * m + 1];
    unsigned long long kk = k1 < k0 ? k1 : k0;
    int idx = (int)(kk & 0xFFFFFFFFull);
    float c = counts[idx];
    c = c < 1.f ? 1.f : c;
    out[e] = scale[e >> 11] * (sums[(size_t)idx * CB_DIM + k] / c);
}

extern "C" void kernel_launch(void* const* d_in, const int* in_sizes, int n_in,
                              void* d_out, int out_size, void* d_ws, size_t ws_size,
                              hipStream_t stream) {
    const float* x  = (const float*)d_in[0];           // [16,2048]
    const float* cb = (const float*)d_in[1];           // [65536,8]
    char* ws = (char*)d_ws;
    float* scale   = (float*)(ws + WS_SCALE);
    unsigned long long* part = (unsigned long long*)(ws + WS_PART);
    float* sums    = (float*)(ws + WS_SUMS);
    float* counts  = (float*)(ws + WS_CNT);
    float* out     = (float*)d_out;

    // 3 dispatches (was 4): prep folded into argmin via the argmax
    // reformulation; each boundary costs ~10us of the stubborn ~47us tail.
    argmin_kernel<<<(M_ROWS / RPB) * 2, AT, 0, stream>>>(x, cb, scale, part, sums, counts);
    accum_kernel <<<(M_ROWS * CB_DIM) / 256, 256, 0, stream>>>(part, x, scale, sums, counts);
    gather_kernel<<<(B_ROWS * X_COLS) / 256, 256, 0, stream>>>(part, sums, counts, scale, out);
}